// Round 6
// baseline (732.579 us; speedup 1.0000x reference)
//
#include <hip/hip_runtime.h>

#define Bb 4
#define Nn 20000
#define Ee 320000
#define CIN 32
#define COUT 32
#define Kk 16
#define Mm 2
#define NB 625          /* target buckets per (b,m) slice, 32 nodes each */
#define NBLK 64         /* sort blocks per batch */
#define CHUNK 5120      /* edges per sort block: 64*5120 = 327680 >= 320000 */

typedef __attribute__((ext_vector_type(8))) short short8;
typedef __attribute__((ext_vector_type(4))) float f32x4;

__device__ __forceinline__ unsigned f2bf(float x) {   // round-half-up bf16 bits
    union { float f; unsigned u; } c; c.f = x;
    return (c.u + 0x8000u) >> 16;
}

// ---------------- kernel 1: prep: transpose f -> fT; pack pb, pn
__global__ __launch_bounds__(256) void prep_fused(
    const float* __restrict__ f,
    const float4* __restrict__ bc4,
    const float4* __restrict__ bs4,
    const float* __restrict__ nodes,
    const float* __restrict__ nrm,
    float* __restrict__ fT,
    float* __restrict__ pb,
    float4* __restrict__ pn) {
    __shared__ float ldsT[32 * 33];
    __shared__ float ldc[32 * 33];
    __shared__ float ldss[32 * 33];
    const int t   = threadIdx.x;
    const int blk = blockIdx.x;            // 2500 blocks
    const int b   = blk / 625;
    const int n0  = (blk % 625) * 32;
    {
        int lane = t & 31, grp = t >> 5;
        #pragma unroll
        for (int r = 0; r < 4; ++r)
            ldsT[(grp + r * 8) * 33 + lane] = f[(b * CIN + grp + r * 8) * Nn + n0 + lane];
        __syncthreads();
        #pragma unroll
        for (int r = 0; r < 4; ++r)
            fT[(b * Nn + n0 + grp + r * 8) * CIN + lane] = ldsT[lane * 33 + grp + r * 8];
    }
    {
        int nl = t >> 3, j4 = t & 7;
        float4 vc = bc4[(b * Nn + n0 + nl) * 8 + j4];
        float4 vs = bs4[(b * Nn + n0 + nl) * 8 + j4];
        float* pc = ldc + nl * 33 + 4 * j4;
        pc[0] = vc.x; pc[1] = vc.y; pc[2] = vc.z; pc[3] = vc.w;
        float* ps = ldss + nl * 33 + 4 * j4;
        ps[0] = vs.x; ps[1] = vs.y; ps[2] = vs.z; ps[3] = vs.w;
        __syncthreads();
        int half = (t >> 2) & 1, u = t & 3;
        #pragma unroll
        for (int m = 0; m < 2; ++m) {
            const float* src = (half ? ldss : ldc) + nl * 33;
            float4 o;
            o.x = src[8 * u + m];     o.y = src[8 * u + 2 + m];
            o.z = src[8 * u + 4 + m]; o.w = src[8 * u + 6 + m];
            *(float4*)(pb + (((b * 2 + m) * Nn + n0 + nl) * 32) + half * 16 + 4 * u) = o;
        }
    }
    const int t0 = blk * 256 + t, S = 2500 * 256;
    for (int i = t0; i < Bb * Nn; i += S) {
        float2 nd = ((const float2*)nodes)[i];
        float2 nv = ((const float2*)nrm)[i];
        pn[i] = make_float4(nd.x, nd.y, nv.x, nv.y);
    }
}

// ---------------- kernel 2: per-block bucket histograms (LDS atomics only)
__global__ __launch_bounds__(256) void hist_kernel(const int4* __restrict__ de4,
                                                   unsigned* __restrict__ hist) {
    __shared__ unsigned h[2 * NB];
    const int blk = blockIdx.x;            // 4*64
    const int b = blk >> 6, sb = blk & 63;
    const int t = threadIdx.x;
    for (int j = t; j < 2 * NB; j += 256) h[j] = 0;
    __syncthreads();
    #pragma unroll 1
    for (int i = 0; i < CHUNK / 256; ++i) {
        int e = sb * CHUNK + i * 256 + t;
        if (e < Ee) {
            int4 d = de4[b * Ee + e];
            atomicAdd(&h[d.x >> 5], 1u);
            atomicAdd(&h[NB + (d.y >> 5)], 1u);
        }
    }
    __syncthreads();
    for (int j = t; j < 2 * NB; j += 256) {
        int m = (j >= NB), bin = j - m * NB;
        hist[((b * 2 + m) * NBLK + sb) * NB + bin] = h[j];
    }
}

// ---------------- kernel 3: scan -> per-(slice,bin,block) bases + bucket starts
__global__ __launch_bounds__(256) void scan_kernel(unsigned* __restrict__ hist,
                                                   unsigned* __restrict__ bstart) {
    __shared__ unsigned col[NB];
    __shared__ unsigned cst[NB + 1];
    const int s = blockIdx.x;              // 8 slices
    const int t = threadIdx.x;
    for (int bin = t; bin < NB; bin += 256) {
        unsigned sum = 0;
        for (int blk = 0; blk < NBLK; ++blk) sum += hist[(s * NBLK + blk) * NB + bin];
        col[bin] = sum;
    }
    __syncthreads();
    if (t == 0) {
        unsigned run = 0;
        for (int bin = 0; bin < NB; ++bin) { cst[bin] = run; run += col[bin]; }
        cst[NB] = run;                     // == Ee
    }
    __syncthreads();
    for (int bin = t; bin <= NB; bin += 256) bstart[s * (NB + 1) + bin] = cst[bin];
    for (int bin = t; bin < NB; bin += 256) {
        unsigned run = cst[bin];
        for (int blk = 0; blk < NBLK; ++blk) {
            unsigned idx = (s * NBLK + blk) * NB + bin;
            unsigned v = hist[idx]; hist[idx] = run; run += v;
        }
    }
}

// ---------------- kernel 4: placement: rec[slot] = {tloc|sn<<5, scale}
__global__ __launch_bounds__(256) void place_kernel(const int4* __restrict__ de4,
                                                    const float4* __restrict__ pn,
                                                    const float* __restrict__ nwt,
                                                    const unsigned* __restrict__ hist,
                                                    uint2* __restrict__ rec) {
    __shared__ unsigned lb[2 * NB];
    const int blk = blockIdx.x;
    const int b = blk >> 6, sb = blk & 63;
    const int t = threadIdx.x;
    for (int j = t; j < 2 * NB; j += 256) {
        int m = (j >= NB), bin = j - m * NB;
        lb[j] = hist[((b * 2 + m) * NBLK + sb) * NB + bin];
    }
    __syncthreads();
    #pragma unroll 1
    for (int i = 0; i < CHUNK / 256; ++i) {
        int e = sb * CHUNK + i * 256 + t;
        if (e >= Ee) continue;
        int4 d = de4[b * Ee + e];
        #pragma unroll
        for (int m = 0; m < 2; ++m) {
            int tn = m ? d.y : d.x;
            int sn = m ? d.w : d.z;
            float4 qt = pn[b * Nn + tn];
            float4 qs = pn[b * Nn + sn];
            float dx = qt.x - qs.x, dy = qt.y - qs.y;
            float r2 = dx * dx + dy * dy + 1e-6f;
            float sc = nwt[(b * Ee + e) * 2 + m] * (dx * qs.z + dy * qs.w) / r2;
            unsigned pos = atomicAdd(&lb[m * NB + (tn >> 5)], 1u);
            rec[(size_t)(b * 2 + m) * Ee + pos] =
                make_uint2((unsigned)((tn & 31) | (sn << 5)), __float_as_uint(sc));
        }
    }
}

// ---------------- kernel 5: gather: block owns (b, bucket); LDS accumulate; no global atomics
__global__ __launch_bounds__(256, 4) void gather_kernel(
    const float4* __restrict__ pb4,
    const float4* __restrict__ fT4,
    const uint2* __restrict__ rec,
    const unsigned* __restrict__ bstart,
    const float* __restrict__ wc,
    const float* __restrict__ wsp,
    const float* __restrict__ w0,
    float4* __restrict__ f_out4) {
    __shared__ float accb[32 * 33];
    __shared__ __align__(16) float spb[4][16 * 68];
    __shared__ __align__(16) float sfs[4][16 * 36];
    __shared__ uint2 wrec[4][16];

    const int jb  = blockIdx.x;            // 8*313 = 2504
    const int xcd = jb & 7;
    const int b   = xcd >> 1;
    const int bin = (jb >> 3) * 2 + (xcd & 1);
    if (bin >= NB) return;

    const int t = threadIdx.x;
    const int wv = t >> 6, l = t & 63;
    const int c = l & 15, q = l >> 4;
    const int kb = (q & 1) * 8, mode = q >> 1;
    const unsigned smask = mode ? 0x80000000u : 0u;

    // B-fragments + w0 for both m
    short8 b00, b01, b10, b11;             // b{m}{half}
    #pragma unroll
    for (int jj = 0; jj < 8; ++jj) {
        int k = q * 8 + jj;
        float wA0, wB0, wA1, wB1;
        if (k < 16) {
            wA0 = 2.0f * wc[(c * Kk + k) * Mm + 0];
            wB0 = 2.0f * wc[((c + 16) * Kk + k) * Mm + 0];
            wA1 = 2.0f * wc[(c * Kk + k) * Mm + 1];
            wB1 = 2.0f * wc[((c + 16) * Kk + k) * Mm + 1];
        } else {
            wA0 = 2.0f * wsp[(c * Kk + k - 16) * Mm + 0];
            wB0 = 2.0f * wsp[((c + 16) * Kk + k - 16) * Mm + 0];
            wA1 = 2.0f * wsp[(c * Kk + k - 16) * Mm + 1];
            wB1 = 2.0f * wsp[((c + 16) * Kk + k - 16) * Mm + 1];
        }
        b00[jj] = (short)f2bf(wA0); b01[jj] = (short)f2bf(wB0);
        b10[jj] = (short)f2bf(wA1); b11[jj] = (short)f2bf(wB1);
    }
    const float a000 = w0[c * Mm + 0] + 1.0f, a010 = w0[(c + 16) * Mm + 0] + 1.0f;
    const float a001 = w0[c * Mm + 1] + 1.0f, a011 = w0[(c + 16) * Mm + 1] + 1.0f;

    const unsigned st0 = bstart[(b * 2 + 0) * (NB + 1) + bin];
    const unsigned en0 = bstart[(b * 2 + 0) * (NB + 1) + bin + 1];
    const unsigned st1 = bstart[(b * 2 + 1) * (NB + 1) + bin];
    const unsigned en1 = bstart[(b * 2 + 1) * (NB + 1) + bin + 1];
    const int cnt0 = (int)(en0 - st0), cnt1 = (int)(en1 - st1);
    const int nt0 = (cnt0 + 15) >> 4, nt1 = (cnt1 + 15) >> 4;
    const int NT = nt0 + nt1;

    for (int i = t; i < 32 * 33; i += 256) accb[i] = 0.0f;
    __syncthreads();

    float* myld = spb[wv];
    float* myfs = sfs[wv];
    const int il = l >> 2, jj4 = l & 3;

    for (int tt = wv; tt < NT; tt += 4) {
        const int mtile = (tt >= nt0);
        const int tl = mtile ? (tt - nt0) : tt;
        const int stm = mtile ? (int)st1 : (int)st0;
        const int cntm = mtile ? cnt1 : cnt0;
        const int base = stm + tl * 16;
        int vcnt = cntm - tl * 16; if (vcnt > 16) vcnt = 16;
        const uint2* recS = rec + (size_t)(b * 2 + mtile) * Ee;

        if (l < 16) {
            int idx = (l < vcnt) ? l : (vcnt - 1);
            wrec[wv][l] = recS[base + idx];
        }
        // ---- stage pb rows (roles: il, jj4) — addresses straight from records
        {
            uint2 wa = wrec[wv][il];
            int tn = bin * 32 + (int)(wa.x & 31u);
            int sn = (int)((wa.x >> 5) & 0x7FFFu);
            int rowT = ((b * 2 + mtile) * Nn + tn) * 8;
            int rowS = ((b * 2 + mtile) * Nn + sn) * 8;
            float4 g0 = pb4[rowT + jj4];
            float4 g1 = pb4[rowT + 4 + jj4];
            float4 g2 = pb4[rowS + jj4];
            float4 g3 = pb4[rowS + 4 + jj4];
            float* row = myld + il * 68;
            *(float4*)(row + 4 * jj4)      = g0;
            *(float4*)(row + 16 + 4 * jj4) = g1;
            *(float4*)(row + 32 + 4 * jj4) = g2;
            *(float4*)(row + 48 + 4 * jj4) = g3;
        }
        // ---- stage fs rows, 16B/lane
        #pragma unroll
        for (int p = 0; p < 2; ++p) {
            int inst = p * 8 + (l >> 3);
            uint2 wf = wrec[wv][inst];
            int snf = (int)((wf.x >> 5) & 0x7FFFu);
            float4 v = fT4[((size_t)b * Nn + snf) * 8 + (l & 7)];
            *(float4*)(myfs + inst * 36 + (l & 7) * 4) = v;
        }
        asm volatile("s_waitcnt lgkmcnt(0)" ::: "memory");

        // ---- A-frag + pack (verified R3 math)
        const float* rr = myld + c * 68;
        float bct[8], bst[8], xx[8], yy[8];
        *(float4*)(bct)     = *(const float4*)(rr + kb);
        *(float4*)(bct + 4) = *(const float4*)(rr + kb + 4);
        *(float4*)(bst)     = *(const float4*)(rr + 16 + kb);
        *(float4*)(bst + 4) = *(const float4*)(rr + 16 + kb + 4);
        const float* sx = rr + 32 + (mode ? 16 : 0) + kb;
        const float* sy = rr + 32 + (mode ? 0 : 16) + kb;
        *(float4*)(xx)     = *(const float4*)(sx);
        *(float4*)(xx + 4) = *(const float4*)(sx + 4);
        *(float4*)(yy)     = *(const float4*)(sy);
        *(float4*)(yy + 4) = *(const float4*)(sy + 4);

        union { short8 s8; unsigned u[4]; } af;
        #pragma unroll
        for (int jp = 0; jp < 4; ++jp) {
            float s0 = __uint_as_float(__float_as_uint(bst[2 * jp])     ^ smask);
            float s1 = __uint_as_float(__float_as_uint(bst[2 * jp + 1]) ^ smask);
            float v0f = fmaf(bct[2 * jp],     xx[2 * jp],     s0 * yy[2 * jp]);
            float v1f = fmaf(bct[2 * jp + 1], xx[2 * jp + 1], s1 * yy[2 * jp + 1]);
            af.u[jp] = f2bf(v0f) | ((__float_as_uint(v1f) + 0x8000u) & 0xffff0000u);
        }
        short8 bfA = mtile ? b10 : b00;
        short8 bfB = mtile ? b11 : b01;
        float a0A = mtile ? a001 : a000;
        float a0B = mtile ? a011 : a010;
        f32x4 zero = {0.f, 0.f, 0.f, 0.f};
        f32x4 d0 = __builtin_amdgcn_mfma_f32_16x16x32_bf16(af.s8, bfA, zero, 0, 0, 0);
        f32x4 d1 = __builtin_amdgcn_mfma_f32_16x16x32_bf16(af.s8, bfB, zero, 0, 0, 0);

        // ---- epilogue: LDS accumulate (lane: inst=4q+r, ch=c / c+16)
        #pragma unroll
        for (int r = 0; r < 4; ++r) {
            int inst = 4 * q + r;
            uint2 wr = wrec[wv][inst];
            float sc = (inst < vcnt) ? __uint_as_float(wr.y) : 0.0f;
            int tl_ = (int)(wr.x & 31u);
            float fs0 = myfs[inst * 36 + c];
            float fs1 = myfs[inst * 36 + c + 16];
            atomicAdd(&accb[tl_ * 33 + c],      (a0A + d0[r]) * fs0 * sc);
            atomicAdd(&accb[tl_ * 33 + c + 16], (a0B + d1[r]) * fs1 * sc);
        }
    }
    __syncthreads();
    // ---- flush: one coalesced 4 KB store; this block exclusively owns the bucket
    {
        int i = t >> 3, jf = t & 7;
        const float* ap = accb + i * 33 + jf * 4;
        float4 v; v.x = ap[0]; v.y = ap[1]; v.z = ap[2]; v.w = ap[3];
        f_out4[((size_t)b * Nn + bin * 32 + i) * 8 + jf] = v;
    }
}

// ---------------- kernel 6: out[b,o,n] = bias[o] + sum_i wk[o,i] * f_out[b,n,i]
__global__ __launch_bounds__(256) void out_kernel(
    const float4* __restrict__ f_out4,
    const float* __restrict__ wk,
    const float* __restrict__ bias,
    float* __restrict__ out) {
    __shared__ float lwk[1024];
    __shared__ float lf[64 * 33];
    int blk  = blockIdx.x;
    int b    = blk / 313;
    int tile = blk % 313;
    int n0   = tile * 64;
    int t    = threadIdx.x;
    #pragma unroll
    for (int r = 0; r < 4; ++r) lwk[r * 256 + t] = wk[r * 256 + t];
    #pragma unroll
    for (int r = 0; r < 2; ++r) {
        int flat = r * 256 + t;
        int nl = flat >> 3, i4 = flat & 7;
        int n  = n0 + nl;
        float4 v = (n < Nn) ? f_out4[((size_t)b * Nn + n) * 8 + i4] : make_float4(0, 0, 0, 0);
        float* p = lf + nl * 33 + 4 * i4;
        p[0] = v.x; p[1] = v.y; p[2] = v.z; p[3] = v.w;
    }
    __syncthreads();
    int nl = t & 63;
    int og = t >> 6;
    int n  = n0 + nl;
    if (n < Nn) {
        #pragma unroll
        for (int r = 0; r < 8; ++r) {
            int o = r * 4 + og;
            float acc = bias[o];
            #pragma unroll
            for (int i = 0; i < 32; ++i) acc += lwk[o * 32 + i] * lf[nl * 33 + i];
            out[(b * COUT + o) * Nn + n] = acc;
        }
    }
}

extern "C" void kernel_launch(void* const* d_in, const int* in_sizes, int n_in,
                              void* d_out, int out_size, void* d_ws, size_t ws_size,
                              hipStream_t stream) {
    const float* f       = (const float*)d_in[0];
    const float* bases_c = (const float*)d_in[1];
    const float* bases_s = (const float*)d_in[2];
    const float* nodes   = (const float*)d_in[4];
    const float* nrm     = (const float*)d_in[5];
    const int*   de      = (const int*)d_in[6];
    const float* nwt     = (const float*)d_in[7];
    const float* wc      = (const float*)d_in[8];
    const float* wsp     = (const float*)d_in[9];
    const float* w0      = (const float*)d_in[10];
    const float* wk      = (const float*)d_in[11];
    const float* bias    = (const float*)d_in[12];
    float* out = (float*)d_out;

    float*    fT     = (float*)d_ws;                          // 2,560,000 f
    float*    pb     = fT + 2560000;                          // 5,120,000 f
    float4*   pn     = (float4*)(pb + 5120000);               // 80,000 f4
    float*    f_out  = (float*)(pn + 80000);                  // 2,560,000 f
    uint2*    rec    = (uint2*)(f_out + 2560000);             // 2,560,000 u2
    unsigned* hist   = (unsigned*)(rec + 2560000);            // 320,000 u
    unsigned* bstart = hist + 320000;                         // 5,008 u
    // total ~64.0 MB of d_ws

    prep_fused<<<2500, 256, 0, stream>>>(f, (const float4*)bases_c,
                                         (const float4*)bases_s, nodes, nrm,
                                         fT, pb, pn);
    hist_kernel<<<Bb * NBLK, 256, 0, stream>>>((const int4*)de, hist);
    scan_kernel<<<8, 256, 0, stream>>>(hist, bstart);
    place_kernel<<<Bb * NBLK, 256, 0, stream>>>((const int4*)de, pn, nwt, hist, rec);
    gather_kernel<<<8 * 313, 256, 0, stream>>>((const float4*)pb, (const float4*)fT,
                                               rec, bstart, wc, wsp, w0,
                                               (float4*)f_out);
    out_kernel<<<Bb * 313, 256, 0, stream>>>((const float4*)f_out, wk, bias, out);
}

// Round 7
// 279.932 us; speedup vs baseline: 2.6170x; 2.6170x over previous
//
#include <hip/hip_runtime.h>
#include <hip/hip_fp16.h>

#define Bb 4
#define Nn 20000
#define Ee 320000
#define CIN 32
#define COUT 32
#define Kk 16
#define Mm 2
#define EPB (Ee / 64)   /* 5000 super-iters (64 instances) per (b,m) slice */
#define WPB 1024        /* waves per (b,m): (2048/8) blocks * 4 waves */

typedef __attribute__((ext_vector_type(8))) short short8;
typedef __attribute__((ext_vector_type(4))) float f32x4;

__device__ __forceinline__ unsigned f2bf(float x) {   // round-half-up bf16 bits
    union { float f; unsigned u; } c; c.f = x;
    return (c.u + 0x8000u) >> 16;
}

// ---------------- kernel 1: prep: transpose f -> fT; pack pb, pn; zero f_out (fp16)
__global__ __launch_bounds__(256) void prep_fused(
    const float* __restrict__ f,
    const float4* __restrict__ bc4,
    const float4* __restrict__ bs4,
    const float* __restrict__ nodes,
    const float* __restrict__ nrm,
    float* __restrict__ fT,
    float4* __restrict__ f_outz,      // fp16 accumulator viewed as float4 for zeroing
    float* __restrict__ pb,
    float4* __restrict__ pn) {
    __shared__ float ldsT[32 * 33];
    __shared__ float ldc[32 * 33];
    __shared__ float ldss[32 * 33];
    const int t   = threadIdx.x;
    const int blk = blockIdx.x;            // 2500 blocks
    const int b   = blk / 625;
    const int n0  = (blk % 625) * 32;
    {
        int lane = t & 31, grp = t >> 5;
        #pragma unroll
        for (int r = 0; r < 4; ++r)
            ldsT[(grp + r * 8) * 33 + lane] = f[(b * CIN + grp + r * 8) * Nn + n0 + lane];
        __syncthreads();
        #pragma unroll
        for (int r = 0; r < 4; ++r)
            fT[(b * Nn + n0 + grp + r * 8) * CIN + lane] = ldsT[lane * 33 + grp + r * 8];
    }
    {
        int nl = t >> 3, j4 = t & 7;
        float4 vc = bc4[(b * Nn + n0 + nl) * 8 + j4];
        float4 vs = bs4[(b * Nn + n0 + nl) * 8 + j4];
        float* pc = ldc + nl * 33 + 4 * j4;
        pc[0] = vc.x; pc[1] = vc.y; pc[2] = vc.z; pc[3] = vc.w;
        float* ps = ldss + nl * 33 + 4 * j4;
        ps[0] = vs.x; ps[1] = vs.y; ps[2] = vs.z; ps[3] = vs.w;
        __syncthreads();
        int half = (t >> 2) & 1, u = t & 3;
        #pragma unroll
        for (int m = 0; m < 2; ++m) {
            const float* src = (half ? ldss : ldc) + nl * 33;
            float4 o;
            o.x = src[8 * u + m];     o.y = src[8 * u + 2 + m];
            o.z = src[8 * u + 4 + m]; o.w = src[8 * u + 6 + m];
            *(float4*)(pb + (((b * 2 + m) * Nn + n0 + nl) * 32) + half * 16 + 4 * u) = o;
        }
    }
    const int t0 = blk * 256 + t, S = 2500 * 256;
    // f_out is Bb*Nn*32 halves = 5.12 MB = 320000 float4
    for (int i = t0; i < 320000; i += S) f_outz[i] = make_float4(0, 0, 0, 0);
    for (int i = t0; i < Bb * Nn; i += S) {
        float2 nd = ((const float2*)nodes)[i];
        float2 nv = ((const float2*)nrm)[i];
        pn[i] = make_float4(nd.x, nd.y, nv.x, nv.y);
    }
}

// ---------------- kernel 2: edge scatter, MFMA matvec, pipelined, fp16 pk atomics
__global__ __launch_bounds__(256, 4) void edge_kernel(
    const float4* __restrict__ pb4,
    const float4* __restrict__ pn,
    const float* __restrict__ fT,
    const int4* __restrict__ de4,
    const float* __restrict__ nwt,
    const float* __restrict__ wc,
    const float* __restrict__ wsp,
    const float* __restrict__ w0,
    __half* __restrict__ f_out) {
    __shared__ __align__(16) float spb[4][16 * 68];   // 17408 B
    const int t  = threadIdx.x;
    const int wv = t >> 6;
    const int l  = t & 63;
    const int c  = l & 15;
    const int q  = l >> 4;
    const int kb = (q & 1) * 8;
    const int mode = q >> 1;
    const unsigned smask = mode ? 0x80000000u : 0u;
    const int bm = blockIdx.x & 7;
    const int b  = bm >> 1, m = bm & 1;
    const int wid = (blockIdx.x >> 3) * 4 + wv;       // 0..1023
    const int rowoff = (b + m) * Nn;                  // bt -> pb row base add

    // loop-invariant B fragments (weights, bf16): B[k=q*8+j][ch]
    short8 bf0, bf1;
    #pragma unroll
    for (int j = 0; j < 8; ++j) {
        int k = q * 8 + j;
        float w0v, w1v;
        if (k < 16) {
            w0v = 2.0f * wc[(c * Kk + k) * Mm + m];
            w1v = 2.0f * wc[((c + 16) * Kk + k) * Mm + m];
        } else {
            w0v = 2.0f * wsp[(c * Kk + (k - 16)) * Mm + m];
            w1v = 2.0f * wsp[((c + 16) * Kk + (k - 16)) * Mm + m];
        }
        bf0[j] = (short)f2bf(w0v);
        bf1[j] = (short)f2bf(w1v);
    }
    const float acc00 = w0[c * Mm + m] + 1.0f;
    const float acc01 = w0[(c + 16) * Mm + m] + 1.0f;

    float* myld = spb[wv];
    const int il = l >> 2, jj4 = l & 3;
    const int ceven = ((c & 1) == 0);
    const int choff = ceven ? c : (c + 15);           // pk-atomic halfword offset

    // pipeline state
    float scale; int bt, bs;
    float4 g0, g1, g2, g3;
    float fa[4], fb[4];
    int4  d4n;
    int   btn, bsn;
    float dxn, dyn, nzn, nwn2, nwn;

    int s = wid;
    {
        int e = s * 64 + l;
        int4 d4 = de4[b * Ee + e];
        int tn = m ? d4.y : d4.x;
        int sn = m ? d4.w : d4.z;
        bt = b * Nn + tn;
        bs = b * Nn + sn;
        float4 qt = pn[bt];
        float4 qs = pn[bs];
        float dx = qt.x - qs.x, dy = qt.y - qs.y;
        float r2 = dx * dx + dy * dy + 1e-6f;
        scale = nwt[(b * Ee + e) * Mm + m] * (dx * qs.z + dy * qs.w) / r2;
        int bta = __shfl(bt, il), bsa = __shfl(bs, il);
        int pTa = (bta + rowoff) * 8, pSa = (bsa + rowoff) * 8;
        g0 = pb4[pTa + jj4];     g1 = pb4[pTa + 4 + jj4];
        g2 = pb4[pSa + jj4];     g3 = pb4[pSa + 4 + jj4];
        #pragma unroll
        for (int r = 0; r < 4; ++r) {
            int bsr = __shfl(bs, 4 * q + r);
            fa[r] = fT[bsr * CIN + c];
            fb[r] = fT[bsr * CIN + c + 16];
        }
    }

    for (; s < EPB; s += WPB) {
        const bool last = (s + WPB >= EPB);
        #pragma unroll
        for (int tau = 0; tau < 4; ++tau) {
            // ---- 1. commit prefetched pb rows to LDS
            float* row = myld + il * 68;
            *(float4*)(row + 4 * jj4)      = g0;
            *(float4*)(row + 16 + 4 * jj4) = g1;
            *(float4*)(row + 32 + 4 * jj4) = g2;
            *(float4*)(row + 48 + 4 * jj4) = g3;

            // ---- 2. A-frag read + pack + MFMA (verified numerics R3-R5)
            const float* rr = myld + c * 68;
            float bct[8], bst[8], xx[8], yy[8];
            *(float4*)(bct)     = *(const float4*)(rr + kb);
            *(float4*)(bct + 4) = *(const float4*)(rr + kb + 4);
            *(float4*)(bst)     = *(const float4*)(rr + 16 + kb);
            *(float4*)(bst + 4) = *(const float4*)(rr + 16 + kb + 4);
            const float* sx = rr + 32 + (mode ? 16 : 0) + kb;
            const float* sy = rr + 32 + (mode ? 0 : 16) + kb;
            *(float4*)(xx)     = *(const float4*)(sx);
            *(float4*)(xx + 4) = *(const float4*)(sx + 4);
            *(float4*)(yy)     = *(const float4*)(sy);
            *(float4*)(yy + 4) = *(const float4*)(sy + 4);

            union { short8 s8; unsigned u[4]; } af;
            #pragma unroll
            for (int jp = 0; jp < 4; ++jp) {
                float s0 = __uint_as_float(__float_as_uint(bst[2 * jp])     ^ smask);
                float s1 = __uint_as_float(__float_as_uint(bst[2 * jp + 1]) ^ smask);
                float v0f = fmaf(bct[2 * jp],     xx[2 * jp],     s0 * yy[2 * jp]);
                float v1f = fmaf(bct[2 * jp + 1], xx[2 * jp + 1], s1 * yy[2 * jp + 1]);
                af.u[jp] = f2bf(v0f) | ((__float_as_uint(v1f) + 0x8000u) & 0xffff0000u);
            }
            f32x4 zero = {0.f, 0.f, 0.f, 0.f};
            f32x4 d0 = __builtin_amdgcn_mfma_f32_16x16x32_bf16(af.s8, bf0, zero, 0, 0, 0);
            f32x4 d1 = __builtin_amdgcn_mfma_f32_16x16x32_bf16(af.s8, bf1, zero, 0, 0, 0);

            // ---- 3. epilogue values (consume fs BEFORE prefetch overwrites)
            float val0[4], val1[4];
            int   btr[4];
            #pragma unroll
            for (int r = 0; r < 4; ++r) {
                int srcl = tau * 16 + 4 * q + r;
                float sc = __shfl(scale, srcl);
                btr[r]   = __shfl(bt, srcl);
                val0[r] = (acc00 + d0[r]) * fa[r] * sc;
                val1[r] = (acc01 + d1[r]) * fb[r] * sc;
            }

            // ---- 4. geometry pipeline for next super-iter
            if (tau == 1 && !last)
                d4n = de4[b * Ee + (s + WPB) * 64 + l];
            if (tau == 2 && !last) {
                int tn = m ? d4n.y : d4n.x;
                int sn = m ? d4n.w : d4n.z;
                btn = b * Nn + tn;
                bsn = b * Nn + sn;
                float4 qt = pn[btn];
                float4 qs = pn[bsn];
                dxn = qt.x - qs.x; dyn = qt.y - qs.y;
                nzn = qs.z; nwn2 = qs.w;
                nwn = nwt[(b * Ee + (s + WPB) * 64 + l) * Mm + m];
            }

            // ---- 5. prefetch next tile (pb rows + fs) BEFORE atomics
            if (tau < 3 || !last) {
                int ntau;
                if (tau == 3) {
                    float r2 = dxn * dxn + dyn * dyn + 1e-6f;
                    scale = nwn * (dxn * nzn + dyn * nwn2) / r2;
                    bt = btn; bs = bsn;
                    ntau = 0;
                } else {
                    ntau = tau + 1;
                }
                int srcA = ntau * 16 + il;
                int bta = __shfl(bt, srcA), bsa = __shfl(bs, srcA);
                int pTa = (bta + rowoff) * 8, pSa = (bsa + rowoff) * 8;
                g0 = pb4[pTa + jj4];     g1 = pb4[pTa + 4 + jj4];
                g2 = pb4[pSa + jj4];     g3 = pb4[pSa + 4 + jj4];
                #pragma unroll
                for (int r = 0; r < 4; ++r) {
                    int bsr = __shfl(bs, ntau * 16 + 4 * q + r);
                    fa[r] = fT[bsr * CIN + c];
                    fb[r] = fT[bsr * CIN + c + 16];
                }
            }

            // ---- 6. pk-fp16 atomics last (1 segment / instance)
            __builtin_amdgcn_sched_barrier(0);
            #pragma unroll
            for (int r = 0; r < 4; ++r) {
                float n0 = __shfl_xor(val0[r], 1);   // neighbor's ch c^1 value
                float n1 = __shfl_xor(val1[r], 1);   // neighbor's ch (c^1)+16 value
                __half2 hv = ceven ? __floats2half2_rn(val0[r], n0)
                                   : __floats2half2_rn(n1, val1[r]);
                unsafeAtomicAdd((__half2*)(f_out + (size_t)btr[r] * CIN + choff), hv);
            }
        }
    }
}

// ---------------- kernel 3: out[b,o,n] = bias[o] + sum_i wk[o,i] * f_out[b,n,i]
__global__ __launch_bounds__(256) void out_kernel(
    const float4* __restrict__ f_out4,    // fp16 data viewed as float4 (8 halves)
    const float* __restrict__ wk,
    const float* __restrict__ bias,
    float* __restrict__ out) {
    __shared__ float lwk[1024];
    __shared__ float lf[64 * 33];
    int blk  = blockIdx.x;
    int b    = blk / 313;
    int tile = blk % 313;
    int n0   = tile * 64;
    int t    = threadIdx.x;
    #pragma unroll
    for (int r = 0; r < 4; ++r) lwk[r * 256 + t] = wk[r * 256 + t];
    {
        // 64 nodes x 32 ch x 2B = 4 KB = 256 x 16B
        int nl = t >> 2, i8 = t & 3;
        int n  = n0 + nl;
        union { float4 v; __half2 h[4]; } u;
        u.v = (n < Nn) ? f_out4[((size_t)b * Nn + n) * 4 + i8]
                       : make_float4(0, 0, 0, 0);
        float* p = lf + nl * 33 + i8 * 8;
        #pragma unroll
        for (int j = 0; j < 4; ++j) {
            float2 fj = __half22float2(u.h[j]);
            p[2 * j]     = fj.x;
            p[2 * j + 1] = fj.y;
        }
    }
    __syncthreads();
    int nl = t & 63;
    int og = t >> 6;
    int n  = n0 + nl;
    if (n < Nn) {
        #pragma unroll
        for (int r = 0; r < 8; ++r) {
            int o = r * 4 + og;
            float acc = bias[o];
            #pragma unroll
            for (int i = 0; i < 32; ++i) acc += lwk[o * 32 + i] * lf[nl * 33 + i];
            out[(b * COUT + o) * Nn + n] = acc;
        }
    }
}

extern "C" void kernel_launch(void* const* d_in, const int* in_sizes, int n_in,
                              void* d_out, int out_size, void* d_ws, size_t ws_size,
                              hipStream_t stream) {
    const float* f       = (const float*)d_in[0];
    const float* bases_c = (const float*)d_in[1];
    const float* bases_s = (const float*)d_in[2];
    const float* nodes   = (const float*)d_in[4];
    const float* nrm     = (const float*)d_in[5];
    const int*   de      = (const int*)d_in[6];
    const float* nwt     = (const float*)d_in[7];
    const float* wc      = (const float*)d_in[8];
    const float* wsp     = (const float*)d_in[9];
    const float* w0      = (const float*)d_in[10];
    const float* wk      = (const float*)d_in[11];
    const float* bias    = (const float*)d_in[12];
    float* out = (float*)d_out;

    float*  fT    = (float*)d_ws;                              // 2,560,000 f
    float*  pb    = fT + 2560000;                              // 5,120,000 f
    float4* pn    = (float4*)(pb + 5120000);                   // 80,000 f4
    __half* f_out = (__half*)(pn + 80000);                     // 2,560,000 halves (5.12 MB)

    prep_fused<<<2500, 256, 0, stream>>>(f, (const float4*)bases_c,
                                         (const float4*)bases_s, nodes, nrm,
                                         fT, (float4*)f_out, pb, pn);
    edge_kernel<<<2048, 256, 0, stream>>>((const float4*)pb, pn, fT,
                                          (const int4*)de, nwt, wc, wsp, w0, f_out);
    out_kernel<<<Bb * 313, 256, 0, stream>>>((const float4*)f_out, wk, bias, out);
}